// Round 10
// baseline (388.749 us; speedup 1.0000x reference)
//
#include <hip/hip_runtime.h>
#include <hip/hip_bf16.h>

typedef __attribute__((ext_vector_type(4))) float f32x4;
typedef __attribute__((ext_vector_type(8))) short s16x8;
typedef __attribute__((ext_vector_type(4))) short s16x4;

#define MFMA16(A, B, C) __builtin_amdgcn_mfma_f32_16x16x32_bf16((A), (B), (C), 0, 0, 0)

#define GLDS16(gsrc, ldst) __builtin_amdgcn_global_load_lds(                   \
    (const __attribute__((address_space(1))) void*)(gsrc),                    \
    (__attribute__((address_space(3))) void*)(ldst), 16, 0, 0)

__device__ __forceinline__ ushort f2bf(float f) {
    __hip_bfloat16 h = __float2bfloat16(f);
    return *reinterpret_cast<ushort*>(&h);
}

// branchless exact GELU via Abramowitz-Stegun 7.1.26 erf (|err| <= 1.5e-7)
__device__ __forceinline__ float gelu_exact(float x) {
    float z = 0.70710678118f * x;
    float az = fabsf(z);
    float t = 1.0f / fmaf(0.3275911f, az, 1.0f);
    float poly = t * (0.254829592f + t * (-0.284496736f + t * (1.421413741f +
                 t * (-1.453152027f + t * 1.061405429f))));
    float e = __expf(-az * az);
    float erfv = copysignf(1.0f - poly * e, z);
    return 0.5f * x * (1.0f + erfv);
}

// ---------------- convert fp32 -> bf16 (vectorized x4) ----------------
__global__ void k_cvt(const float* __restrict__ in, ushort* __restrict__ out, int n) {
    int i = (blockIdx.x * 256 + threadIdx.x) * 4;
    if (i + 3 >= n) return;
    float4 v = *(const float4*)(in + i);
    ushort4 o;
    o.x = f2bf(v.x); o.y = f2bf(v.y); o.z = f2bf(v.z); o.w = f2bf(v.w);
    *(ushort4*)(out + i) = o;
}

// ---------------- transpose weight [K,N] f32 -> [N,K] bf16 ----------------
__global__ void k_twT(const float* __restrict__ w, ushort* __restrict__ wt, int K, int N) {
    __shared__ float tile[32][33];
    int k0 = blockIdx.x * 32, n0 = blockIdx.y * 32;
    int tx = threadIdx.x & 31, ty = threadIdx.x >> 5;   // 32 x 8
    #pragma unroll
    for (int i = ty; i < 32; i += 8)
        tile[i][tx] = w[(size_t)(k0 + i) * N + n0 + tx];
    __syncthreads();
    #pragma unroll
    for (int i = ty; i < 32; i += 8)
        wt[(size_t)(n0 + i) * K + k0 + tx] = f2bf(tile[tx][i]);
}

// ---------------- zero chunk 9 of Vt (keys 288..319 region) ----------------
// Vt tiled layout: [(b*8+h)][kc(10)][v(256)][k32(32)] ushort
__global__ void k_zeroV9(ushort* __restrict__ Vt) {
    int i = (blockIdx.x * 256 + threadIdx.x) * 8;   // < 512*8192
    int bh = i >> 13, within = i & 8191;
    s16x8 z = {0, 0, 0, 0, 0, 0, 0, 0};
    *(s16x8*)(Vt + ((size_t)bh * 10 + 9) * 8192 + within) = z;
}

// ---------------- GEMM: A[M,K]bf16 @ BT[*,K]bf16^T ----------------
// 3-deep pipeline, counted vmcnt(4) (T4): tile t+2 in flight across barriers,
// one s_barrier per K-step. LDS 48 KiB (3 bufs) -> 3 blocks/CU.
// OUT=0 (fused stage 1): ny<4 -> G_bf bf16 [19200][512] (+b_gen);
//                        ny>=4 -> Vt tiled bf16 (+b_val).
// OUT=2 (stage 3): f32 [19200][512] = acc + b_out + resid.
template <int OUT>
__global__ __launch_bounds__(256) void k_gemm(const ushort* __restrict__ A,
                                              const ushort* __restrict__ BT,
                                              const float* __restrict__ b1,
                                              const float* __restrict__ b2,
                                              void* __restrict__ o1,
                                              void* __restrict__ o2,
                                              int K, int GY) {
    __shared__ __align__(16) ushort As[3][128][32];
    __shared__ __align__(16) ushort Bs[3][128][32];
    int id = blockIdx.x;
    int xcd = id & 7, s = id >> 3;          // s in [0, 19*GY)
    int mxl = s / GY, ny = s - mxl * GY;
    int mx = xcd * 19 + mxl;
    if (mx >= 150) return;
    int m0 = mx * 128, n0 = ny * 128;

    int t = threadIdx.x, l = t & 63, w = t >> 6;
    int wm = (w >> 1) * 64, wn = (w & 1) * 64;
    int lr = l & 15, lg = l >> 4;

    auto stage = [&](int it, int buf) {
        ushort* AsF = &As[buf][0][0];
        ushort* BsF = &Bs[buf][0][0];
        int k0 = it * 32;
        #pragma unroll
        for (int c = 0; c < 2; ++c) {
            int cb = w * 128 + c * 64;          // wave-uniform chunk base
            int ch = cb + l;
            int row = ch >> 2, col = (ch & 3) * 8;
            GLDS16(A + (size_t)(m0 + row) * K + k0 + col, AsF + (size_t)cb * 8);
            GLDS16(BT + (size_t)(n0 + row) * K + k0 + col, BsF + (size_t)cb * 8);
        }
    };

    f32x4 acc[4][4];
    #pragma unroll
    for (int i = 0; i < 4; ++i)
        #pragma unroll
        for (int j = 0; j < 4; ++j)
            acc[i][j] = (f32x4){0.f, 0.f, 0.f, 0.f};

    int nit = K >> 5;
    stage(0, 0);
    stage(1, 1);

    int cur = 0;
    for (int it = 0; it < nit; ++it) {
        // drain oldest tile (4 glds) + all own LDS reads, then sync
        if (it + 1 < nit) asm volatile("s_waitcnt vmcnt(4) lgkmcnt(0)" ::: "memory");
        else              asm volatile("s_waitcnt vmcnt(0) lgkmcnt(0)" ::: "memory");
        __builtin_amdgcn_s_barrier();
        if (it + 2 < nit) stage(it + 2, cur == 0 ? 2 : cur - 1);

        s16x8 af[4], bfr[4];
        #pragma unroll
        for (int i = 0; i < 4; ++i) af[i] = *(const s16x8*)(&As[cur][wm + i * 16 + lr][lg * 8]);
        #pragma unroll
        for (int j = 0; j < 4; ++j) bfr[j] = *(const s16x8*)(&Bs[cur][wn + j * 16 + lr][lg * 8]);
        #pragma unroll
        for (int i = 0; i < 4; ++i)
            #pragma unroll
            for (int j = 0; j < 4; ++j)
                acc[i][j] = MFMA16(af[i], bfr[j], acc[i][j]);
        cur = (cur == 2) ? 0 : cur + 1;
    }

    if (OUT == 0) {
        if (ny < 4) {
            ushort* G = (ushort*)o1;
            #pragma unroll
            for (int i = 0; i < 4; ++i)
                #pragma unroll
                for (int j = 0; j < 4; ++j) {
                    int col = n0 + wn + j * 16 + lr;
                    float bv = b1[col];
                    #pragma unroll
                    for (int r = 0; r < 4; ++r) {
                        int row = m0 + wm + i * 16 + lg * 4 + r;
                        G[(size_t)row * 512 + col] = f2bf(acc[i][j][r] + bv);
                    }
                }
        } else {
            ushort* Vt = (ushort*)o2;
            #pragma unroll
            for (int i = 0; i < 4; ++i)
                #pragma unroll
                for (int j = 0; j < 4; ++j) {
                    int colv = (n0 - 512) + wn + j * 16 + lr;
                    float bv = b2[colv];
                    int hh = colv >> 8, v = colv & 255;
                    #pragma unroll
                    for (int r = 0; r < 4; ++r) {
                        int row = m0 + wm + i * 16 + lg * 4 + r;
                        int bb = row / 300, key = row - bb * 300;
                        size_t addr = (((size_t)(bb * 8 + hh) * 10 + (key >> 5)) * 8192)
                                      + v * 32 + (key & 31);
                        Vt[addr] = f2bf(acc[i][j][r] + bv);
                    }
                }
        }
    } else {
        float* out = (float*)o1;
        #pragma unroll
        for (int i = 0; i < 4; ++i)
            #pragma unroll
            for (int j = 0; j < 4; ++j) {
                int col = n0 + wn + j * 16 + lr;
                float bv = b1[col];
                #pragma unroll
                for (int r = 0; r < 4; ++r) {
                    int row = m0 + wm + i * 16 + lg * 4 + r;
                    size_t idx = (size_t)row * 512 + col;
                    out[idx] = acc[i][j][r] + bv + b2[idx];
                }
            }
    }
}

// ---------------- fused attention ----------------
// Scores: per-wave private P rows (streamed no-max exp, bf16, XOR-swizzled LDS).
// PV: waves split by v-range (wave w owns v in [w*64, w*64+64) for ALL 64 q)
// -> V slice read ONCE per block straight from L2, no staging, ONE barrier.
// launch_bounds(256,5): cap ~102 arch VGPR (+64 acc) -> aim 3 waves/SIMD.
__global__ __launch_bounds__(256, 5) void k_attn(const ushort* __restrict__ qf_bf,
                                                 const ushort* __restrict__ G_bf,
                                                 const ushort* __restrict__ Vt,
                                                 const float* __restrict__ wb,
                                                 const float* __restrict__ bias,
                                                 ushort* __restrict__ O) {
    __shared__ __align__(16) ushort P[64 * 320];   // 40,960 B swizzled
    __shared__ float invL[64];
    int id = blockIdx.x;
    int xcd = id & 7, s = id >> 3;        // s in [0,320)
    int h = s / 40; int r2 = s - h * 40;
    int bi = r2 / 5, qt = r2 - bi * 5;
    int b = xcd * 8 + bi;

    int t = threadIdx.x, l = t & 63, w = t >> 6;
    int lr = l & 15, lg = l >> 4;

    // swizzled P address: q in [0,64), k in [0,320); preserves 8B alignment
    auto p_addr = [&](int q, int k) -> ushort* {
        int byte = (q * 640 + k * 2) ^ ((q & 15) << 4);
        return (ushort*)((char*)P + byte);
    };

    // Q fragment (B operand): col = q = lane&15
    int qr = min(qt * 64 + w * 16 + lr, 299);
    const ushort* qp = qf_bf + ((size_t)(b * 300 + qr)) * 512 + h * 64 + lg * 8;
    s16x8 q0 = *(const s16x8*)(qp);
    s16x8 q1 = *(const s16x8*)(qp + 32);

    // ---- scores^T streamed: gelu -> exp -> pack -> P LDS write ----
    int qq = w * 16 + lr;
    float ssum = 0.f;
    #pragma unroll
    for (int kt = 0; kt < 19; ++kt) {
        int key = kt * 16 + lr;
        int kcl = min(key, 299);
        const ushort* gp = G_bf + ((size_t)(b * 300 + kcl)) * 512 + h * 64 + lg * 8;
        s16x8 g0 = *(const s16x8*)(gp);
        s16x8 g1 = *(const s16x8*)(gp + 32);
        f32x4 a = (f32x4){0.f, 0.f, 0.f, 0.f};
        a = MFMA16(g0, q0, a);
        a = MFMA16(g1, q1, a);
        int k0 = kt * 16 + lg * 4;
        int k0c = min(k0, 296);
        size_t bidx = ((size_t)h * 300 + qr) * 300 + k0c;
        float4 wv = *(const float4*)(wb + bidx);
        float4 bv = *(const float4*)(bias + bidx);
        bool vmask = (kt < 18) || (lg < 3);
        s16x4 pw;
        #pragma unroll
        for (int r = 0; r < 4; ++r) {
            float x = a[r] * (&wv.x)[r] + (&bv.x)[r];
            float p = vmask ? __expf(gelu_exact(x)) : 0.f;
            ssum += p;
            pw[r] = (short)f2bf(p);
        }
        *(s16x4*)p_addr(qq, k0) = pw;
    }
    // zero pad keys 304..319 -- per-wave rows only (no cross-wave writes)
    *(s16x4*)p_addr(w * 16 + (l >> 2), 304 + (l & 3) * 4) = (s16x4){0, 0, 0, 0};

    // denominator across lg groups; publish per-row 1/sum
    ssum += __shfl_xor(ssum, 16);
    ssum += __shfl_xor(ssum, 32);
    if (lg == 0) invL[qq] = 1.0f / ssum;

    __syncthreads();   // the ONLY barrier: P + invL visible to all waves

    // ---- PV: wave w owns v in [w*64, w*64+64) for all 64 q ----
    f32x4 acc[4][4];   // [qg][nt]
    #pragma unroll
    for (int qg = 0; qg < 4; ++qg)
        #pragma unroll
        for (int nt = 0; nt < 4; ++nt)
            acc[qg][nt] = (f32x4){0.f, 0.f, 0.f, 0.f};

    const ushort* vbase = Vt + (size_t)(b * 8 + h) * 81920
                          + (size_t)(w * 64) * 32 + lg * 8;
    #pragma unroll
    for (int kc = 0; kc < 10; ++kc) {
        s16x8 vb[4], pa[4];
        #pragma unroll
        for (int nt = 0; nt < 4; ++nt)
            vb[nt] = *(const s16x8*)(vbase + (size_t)kc * 8192 + (nt * 16 + lr) * 32);
        #pragma unroll
        for (int qg = 0; qg < 4; ++qg)
            pa[qg] = *(const s16x8*)p_addr(qg * 16 + lr, kc * 32 + lg * 8);
        #pragma unroll
        for (int qg = 0; qg < 4; ++qg)
            #pragma unroll
            for (int nt = 0; nt < 4; ++nt)
                acc[qg][nt] = MFMA16(pa[qg], vb[nt], acc[qg][nt]);
    }

    // ---- normalize + store: q = qt*64 + qg*16 + lg*4 + r, v = w*64 + nt*16 + lr
    #pragma unroll
    for (int qg = 0; qg < 4; ++qg)
        #pragma unroll
        for (int r = 0; r < 4; ++r) {
            int qloc = qg * 16 + lg * 4 + r;
            int q = qt * 64 + qloc;
            if (q < 300) {
                float iv = invL[qloc];
                #pragma unroll
                for (int nt = 0; nt < 4; ++nt) {
                    int v = w * 64 + nt * 16 + lr;
                    O[((size_t)(b * 300 + q)) * 2048 + h * 256 + v] =
                        f2bf(acc[qg][nt][r] * iv);
                }
            }
        }
}

extern "C" void kernel_launch(void* const* d_in, const int* in_sizes, int n_in,
                              void* d_out, int out_size, void* d_ws, size_t ws_size,
                              hipStream_t stream) {
    const float* qf    = (const float*)d_in[0];
    const float* bias  = (const float*)d_in[1];
    const float* W_gen = (const float*)d_in[2];
    const float* b_gen = (const float*)d_in[3];
    const float* W_val = (const float*)d_in[4];
    const float* b_val = (const float*)d_in[5];
    const float* W_out = (const float*)d_in[6];
    const float* b_out = (const float*)d_in[7];
    const float* wb    = (const float*)d_in[8];
    float* out = (float*)d_out;

    char* ws = (char*)d_ws;
    ushort* qf_bf = (ushort*)(ws);                       // 19,660,800 B
    ushort* G_bf  = (ushort*)(ws + 19660800);            // 19,660,800 B
    ushort* Vt    = (ushort*)(ws + 39321600);            // 83,886,080 B (tiled)
    ushort* O_bf  = (ushort*)(ws + 123207680);           // 78,643,200 B
    ushort* WgvT  = (ushort*)(ws + 201850880);           // 2,621,440 B = [2560][512]
    ushort* WoT   = (ushort*)(ws + 204472320);           // 2,097,152 B

    // stage 0: conversions / transposes / pad-zero
    k_cvt<<<dim3(9600), dim3(256), 0, stream>>>(qf, qf_bf, 9830400);
    k_twT<<<dim3(16, 16), dim3(256), 0, stream>>>(W_gen, WgvT, 512, 512);
    k_twT<<<dim3(16, 64), dim3(256), 0, stream>>>(W_val, WgvT + 512 * 512, 512, 2048);
    k_twT<<<dim3(64, 16), dim3(256), 0, stream>>>(W_out, WoT, 2048, 512);
    k_zeroV9<<<dim3(2048), dim3(256), 0, stream>>>(Vt);

    // stage 1 (fused): [G | V] = qf @ [W_gen | W_val] + [b_gen | b_val]
    k_gemm<0><<<dim3(152 * 20), dim3(256), 0, stream>>>(qf_bf, WgvT, b_gen, b_val,
                                                        G_bf, Vt, 512, 20);

    // stage 2: fused attention
    k_attn<<<dim3(2560), dim3(256), 0, stream>>>(qf_bf, G_bf, Vt, wb, bias, O_bf);

    // stage 3: out = O @ W_out + b_out + qf
    k_gemm<2><<<dim3(152 * 4), dim3(256), 0, stream>>>(O_bf, WoT, b_out, qf,
                                                       out, nullptr, 2048, 4);
}

// Round 11
// 309.685 us; speedup vs baseline: 1.2553x; 1.2553x over previous
//
#include <hip/hip_runtime.h>
#include <hip/hip_bf16.h>

typedef __attribute__((ext_vector_type(4))) float f32x4;
typedef __attribute__((ext_vector_type(8))) short s16x8;
typedef __attribute__((ext_vector_type(4))) short s16x4;

#define MFMA16(A, B, C) __builtin_amdgcn_mfma_f32_16x16x32_bf16((A), (B), (C), 0, 0, 0)

#define GLDS16(gsrc, ldst) __builtin_amdgcn_global_load_lds(                   \
    (const __attribute__((address_space(1))) void*)(gsrc),                    \
    (__attribute__((address_space(3))) void*)(ldst), 16, 0, 0)

__device__ __forceinline__ ushort f2bf(float f) {
    __hip_bfloat16 h = __float2bfloat16(f);
    return *reinterpret_cast<ushort*>(&h);
}

// branchless exact GELU via Abramowitz-Stegun 7.1.26 erf (|err| <= 1.5e-7)
__device__ __forceinline__ float gelu_exact(float x) {
    float z = 0.70710678118f * x;
    float az = fabsf(z);
    float t = 1.0f / fmaf(0.3275911f, az, 1.0f);
    float poly = t * (0.254829592f + t * (-0.284496736f + t * (1.421413741f +
                 t * (-1.453152027f + t * 1.061405429f))));
    float e = __expf(-az * az);
    float erfv = copysignf(1.0f - poly * e, z);
    return 0.5f * x * (1.0f + erfv);
}

// ---------------- convert fp32 -> bf16 (vectorized x4) ----------------
__global__ void k_cvt(const float* __restrict__ in, ushort* __restrict__ out, int n) {
    int i = (blockIdx.x * 256 + threadIdx.x) * 4;
    if (i + 3 >= n) return;
    float4 v = *(const float4*)(in + i);
    ushort4 o;
    o.x = f2bf(v.x); o.y = f2bf(v.y); o.z = f2bf(v.z); o.w = f2bf(v.w);
    *(ushort4*)(out + i) = o;
}

// ---------------- transpose weight [K,N] f32 -> [N,K] bf16 ----------------
__global__ void k_twT(const float* __restrict__ w, ushort* __restrict__ wt, int K, int N) {
    __shared__ float tile[32][33];
    int k0 = blockIdx.x * 32, n0 = blockIdx.y * 32;
    int tx = threadIdx.x & 31, ty = threadIdx.x >> 5;   // 32 x 8
    #pragma unroll
    for (int i = ty; i < 32; i += 8)
        tile[i][tx] = w[(size_t)(k0 + i) * N + n0 + tx];
    __syncthreads();
    #pragma unroll
    for (int i = ty; i < 32; i += 8)
        wt[(size_t)(n0 + i) * K + k0 + tx] = f2bf(tile[tx][i]);
}

// ---------------- zero chunk 9 of Vt (keys 288..319 region) ----------------
// Vt tiled layout: [(b*8+h)][kc(10)][v(256)][k32(32)] ushort
__global__ void k_zeroV9(ushort* __restrict__ Vt) {
    int i = (blockIdx.x * 256 + threadIdx.x) * 8;   // < 512*8192
    int bh = i >> 13, within = i & 8191;
    s16x8 z = {0, 0, 0, 0, 0, 0, 0, 0};
    *(s16x8*)(Vt + ((size_t)bh * 10 + 9) * 8192 + within) = z;
}

// ---------------- 256x256 GEMM: A[M,K]bf16 @ BT[N,K]bf16^T ----------------
// 512 threads = 8 waves (2M x 4N); per-wave out 128x64 (acc[8][4]).
// BK=64, dbuf LDS 128 KiB. Pipeline per K-tile:
//   vmcnt(8) ; s_barrier ; compute(buf) ; s_barrier ; stage(t+2 -> buf)
// (stage(t+1) stays in flight across the compute -> counted vmcnt, T4.)
// LDS image XOR-swizzled: byte ^= ((row&7)<<4)  (involution). glds writes
// linearly, so the GLOBAL source is pre-permuted per lane (rule 21); the
// same XOR is applied on ds_read addresses -> <=2-way bank conflicts.
// OUT=0 (fused stage 1): ny<2 -> G_bf [19200][512]+b_gen ; ny>=2 -> Vt+b_val.
// OUT=2 (stage 3): f32 [19200][512] = acc + b1 + resid.
template <int OUT>
__global__ __launch_bounds__(512, 2) void k_gemm256(const ushort* __restrict__ A,
                                                    const ushort* __restrict__ BT,
                                                    const float* __restrict__ b1,
                                                    const float* __restrict__ b2,
                                                    void* __restrict__ o1,
                                                    void* __restrict__ o2,
                                                    int K, int GY) {
    __shared__ __align__(16) ushort As[2][256 * 64];   // 2 x 32 KiB
    __shared__ __align__(16) ushort Bs[2][256 * 64];   // 2 x 32 KiB
    int id = blockIdx.x;
    int xcd = id & 7, s = id >> 3;
    int mxl = s / GY, ny = s - mxl * GY;
    int mx = xcd * 10 + mxl;
    if (mx >= 75) return;
    int m0 = mx * 256, n0g = ny * 256;

    int t = threadIdx.x, l = t & 63, w = t >> 6;
    int wr = w >> 2, wc = w & 3;            // 2 x 4 wave grid
    int lr = l & 15, lg = l >> 4;

    // per-thread logical (row, k-offset) for the 4 staging chunks (swizzle inv)
    int rsrc[4], ksrc[4];
    #pragma unroll
    for (int c8 = 0; c8 < 4; ++c8) {
        int o = (c8 * 512 + t) * 16;
        int op = o ^ (((o >> 7) & 7) << 4);
        rsrc[c8] = op >> 7;                 // 0..255
        ksrc[c8] = (op & 127) >> 1;         // 0..63 (multiple of 8)
    }

    auto stage = [&](int kt, int buf) {
        int k0 = kt * 64;
        ushort* AsB = &As[buf][0];
        ushort* BsB = &Bs[buf][0];
        #pragma unroll
        for (int c8 = 0; c8 < 4; ++c8) {
            int dst = (c8 * 512 + w * 64) * 8;      // wave-uniform, ushorts
            GLDS16(A  + (size_t)(m0 + rsrc[c8]) * K + k0 + ksrc[c8], AsB + dst);
            GLDS16(BT + (size_t)(n0g + rsrc[c8]) * K + k0 + ksrc[c8], BsB + dst);
        }
    };

    f32x4 acc[8][4];
    #pragma unroll
    for (int i = 0; i < 8; ++i)
        #pragma unroll
        for (int j = 0; j < 4; ++j)
            acc[i][j] = (f32x4){0.f, 0.f, 0.f, 0.f};

    int NT = K >> 6;
    stage(0, 0);
    stage(1, 1);

    for (int kt = 0; kt < NT; ++kt) {
        if (kt + 1 < NT) asm volatile("s_waitcnt vmcnt(8)" ::: "memory");
        else             asm volatile("s_waitcnt vmcnt(0)" ::: "memory");
        __builtin_amdgcn_s_barrier();       // tile kt fully in LDS (all waves)

        int cur = kt & 1;
        const char* Ab = (const char*)&As[cur][0];
        const char* Bb = (const char*)&Bs[cur][0];
        #pragma unroll
        for (int ks = 0; ks < 2; ++ks) {
            int kb = (ks * 64 + lg * 16) ^ ((lr & 7) << 4);
            s16x8 af[8], bfv[4];
            #pragma unroll
            for (int rt = 0; rt < 8; ++rt)
                af[rt] = *(const s16x8*)(Ab + (wr * 128 + rt * 16 + lr) * 128 + kb);
            #pragma unroll
            for (int ct = 0; ct < 4; ++ct)
                bfv[ct] = *(const s16x8*)(Bb + (wc * 64 + ct * 16 + lr) * 128 + kb);
            #pragma unroll
            for (int rt = 0; rt < 8; ++rt)
                #pragma unroll
                for (int ct = 0; ct < 4; ++ct)
                    acc[rt][ct] = MFMA16(af[rt], bfv[ct], acc[rt][ct]);
        }

        __builtin_amdgcn_s_barrier();       // all waves done reading buf cur
        if (kt + 2 < NT) stage(kt + 2, cur);
    }

    // ---- epilogue: row = m0 + wr*128 + rt*16 + lg*4 + rr ; col = wc*64+ct*16+lr
    if (OUT == 0) {
        if (n0g < 512) {
            ushort* G = (ushort*)o1;
            #pragma unroll
            for (int rt = 0; rt < 8; ++rt)
                #pragma unroll
                for (int ct = 0; ct < 4; ++ct) {
                    int col = n0g + wc * 64 + ct * 16 + lr;
                    float bv = b1[col];
                    #pragma unroll
                    for (int rr = 0; rr < 4; ++rr) {
                        int row = m0 + wr * 128 + rt * 16 + lg * 4 + rr;
                        G[(size_t)row * 512 + col] = f2bf(acc[rt][ct][rr] + bv);
                    }
                }
        } else {
            ushort* Vt = (ushort*)o2;
            #pragma unroll
            for (int rt = 0; rt < 8; ++rt) {
                int rl0 = m0 + wr * 128 + rt * 16 + lg * 4;   // %4 == 0
                int bb = rl0 / 300, key0 = rl0 - bb * 300;    // key0 %4 == 0
                #pragma unroll
                for (int ct = 0; ct < 4; ++ct) {
                    int colv = n0g - 512 + wc * 64 + ct * 16 + lr;
                    float bv = b2[colv];
                    int hh = colv >> 8, v = colv & 255;
                    s16x4 pw;
                    #pragma unroll
                    for (int rr = 0; rr < 4; ++rr)
                        pw[rr] = (short)f2bf(acc[rt][ct][rr] + bv);
                    size_t addr = (((size_t)(bb * 8 + hh) * 10 + (key0 >> 5)) * 8192)
                                  + v * 32 + (key0 & 31);
                    *(s16x4*)(Vt + addr) = pw;
                }
            }
        }
    } else {
        float* out = (float*)o1;
        #pragma unroll
        for (int rt = 0; rt < 8; ++rt)
            #pragma unroll
            for (int ct = 0; ct < 4; ++ct) {
                int col = n0g + wc * 64 + ct * 16 + lr;
                float bv = b1[col];
                #pragma unroll
                for (int rr = 0; rr < 4; ++rr) {
                    int row = m0 + wr * 128 + rt * 16 + lg * 4 + rr;
                    size_t idx = (size_t)row * 512 + col;
                    out[idx] = acc[rt][ct][rr] + bv + b2[idx];
                }
            }
    }
}

// ---------------- fused attention (r9 version, known-good) ----------------
__global__ __launch_bounds__(256, 4) void k_attn(const ushort* __restrict__ qf_bf,
                                                 const ushort* __restrict__ G_bf,
                                                 const ushort* __restrict__ Vt,
                                                 const float* __restrict__ wb,
                                                 const float* __restrict__ bias,
                                                 ushort* __restrict__ O) {
    __shared__ __align__(16) ushort P[64 * 320];   // 40,960 B swizzled
    __shared__ float invL[64];
    int id = blockIdx.x;
    int xcd = id & 7, s = id >> 3;        // s in [0,320)
    int h = s / 40; int r2 = s - h * 40;
    int bi = r2 / 5, qt = r2 - bi * 5;
    int b = xcd * 8 + bi;

    int t = threadIdx.x, l = t & 63, w = t >> 6;
    int lr = l & 15, lg = l >> 4;

    auto p_addr = [&](int q, int k) -> ushort* {
        int byte = (q * 640 + k * 2) ^ ((q & 15) << 4);
        return (ushort*)((char*)P + byte);
    };

    int qr = min(qt * 64 + w * 16 + lr, 299);
    const ushort* qp = qf_bf + ((size_t)(b * 300 + qr)) * 512 + h * 64 + lg * 8;
    s16x8 q0 = *(const s16x8*)(qp);
    s16x8 q1 = *(const s16x8*)(qp + 32);

    int qq = w * 16 + lr;
    float ssum = 0.f;
    #pragma unroll
    for (int kt = 0; kt < 19; ++kt) {
        int key = kt * 16 + lr;
        int kcl = min(key, 299);
        const ushort* gp = G_bf + ((size_t)(b * 300 + kcl)) * 512 + h * 64 + lg * 8;
        s16x8 g0 = *(const s16x8*)(gp);
        s16x8 g1 = *(const s16x8*)(gp + 32);
        f32x4 a = (f32x4){0.f, 0.f, 0.f, 0.f};
        a = MFMA16(g0, q0, a);
        a = MFMA16(g1, q1, a);
        int k0 = kt * 16 + lg * 4;
        int k0c = min(k0, 296);
        size_t bidx = ((size_t)h * 300 + qr) * 300 + k0c;
        float4 wv = *(const float4*)(wb + bidx);
        float4 bv = *(const float4*)(bias + bidx);
        bool vmask = (kt < 18) || (lg < 3);
        s16x4 pw;
        #pragma unroll
        for (int r = 0; r < 4; ++r) {
            float x = a[r] * (&wv.x)[r] + (&bv.x)[r];
            float p = vmask ? __expf(gelu_exact(x)) : 0.f;
            ssum += p;
            pw[r] = (short)f2bf(p);
        }
        *(s16x4*)p_addr(qq, k0) = pw;
    }
    *(s16x4*)p_addr(w * 16 + (l >> 2), 304 + (l & 3) * 4) = (s16x4){0, 0, 0, 0};

    ssum += __shfl_xor(ssum, 16);
    ssum += __shfl_xor(ssum, 32);
    if (lg == 0) invL[qq] = 1.0f / ssum;

    __syncthreads();   // the ONLY barrier

    f32x4 acc[4][4];   // [qg][nt]
    #pragma unroll
    for (int qg = 0; qg < 4; ++qg)
        #pragma unroll
        for (int nt = 0; nt < 4; ++nt)
            acc[qg][nt] = (f32x4){0.f, 0.f, 0.f, 0.f};

    const ushort* vbase = Vt + (size_t)(b * 8 + h) * 81920
                          + (size_t)(w * 64) * 32 + lg * 8;
    #pragma unroll
    for (int kc = 0; kc < 10; ++kc) {
        s16x8 vb[4], pa[4];
        #pragma unroll
        for (int nt = 0; nt < 4; ++nt)
            vb[nt] = *(const s16x8*)(vbase + (size_t)kc * 8192 + (nt * 16 + lr) * 32);
        #pragma unroll
        for (int qg = 0; qg < 4; ++qg)
            pa[qg] = *(const s16x8*)p_addr(qg * 16 + lr, kc * 32 + lg * 8);
        #pragma unroll
        for (int qg = 0; qg < 4; ++qg)
            #pragma unroll
            for (int nt = 0; nt < 4; ++nt)
                acc[qg][nt] = MFMA16(pa[qg], vb[nt], acc[qg][nt]);
    }

    #pragma unroll
    for (int qg = 0; qg < 4; ++qg)
        #pragma unroll
        for (int r = 0; r < 4; ++r) {
            int qloc = qg * 16 + lg * 4 + r;
            int q = qt * 64 + qloc;
            if (q < 300) {
                float iv = invL[qloc];
                #pragma unroll
                for (int nt = 0; nt < 4; ++nt) {
                    int v = w * 64 + nt * 16 + lr;
                    O[((size_t)(b * 300 + q)) * 2048 + h * 256 + v] =
                        f2bf(acc[qg][nt][r] * iv);
                }
            }
        }
}

extern "C" void kernel_launch(void* const* d_in, const int* in_sizes, int n_in,
                              void* d_out, int out_size, void* d_ws, size_t ws_size,
                              hipStream_t stream) {
    const float* qf    = (const float*)d_in[0];
    const float* bias  = (const float*)d_in[1];
    const float* W_gen = (const float*)d_in[2];
    const float* b_gen = (const float*)d_in[3];
    const float* W_val = (const float*)d_in[4];
    const float* b_val = (const float*)d_in[5];
    const float* W_out = (const float*)d_in[6];
    const float* b_out = (const float*)d_in[7];
    const float* wb    = (const float*)d_in[8];
    float* out = (float*)d_out;

    char* ws = (char*)d_ws;
    ushort* qf_bf = (ushort*)(ws);                       // 19,660,800 B
    ushort* G_bf  = (ushort*)(ws + 19660800);            // 19,660,800 B
    ushort* Vt    = (ushort*)(ws + 39321600);            // 83,886,080 B (tiled)
    ushort* O_bf  = (ushort*)(ws + 123207680);           // 78,643,200 B
    ushort* WgvT  = (ushort*)(ws + 201850880);           // 2,621,440 B = [2560][512]
    ushort* WoT   = (ushort*)(ws + 204472320);           // 2,097,152 B

    // stage 0: conversions / transposes / pad-zero
    k_cvt<<<dim3(9600), dim3(256), 0, stream>>>(qf, qf_bf, 9830400);
    k_twT<<<dim3(16, 16), dim3(256), 0, stream>>>(W_gen, WgvT, 512, 512);
    k_twT<<<dim3(16, 64), dim3(256), 0, stream>>>(W_val, WgvT + 512 * 512, 512, 2048);
    k_twT<<<dim3(64, 16), dim3(256), 0, stream>>>(W_out, WoT, 2048, 512);
    k_zeroV9<<<dim3(2048), dim3(256), 0, stream>>>(Vt);

    // stage 1 (fused): [G | V] = qf @ [W_gen | W_val] + [b_gen | b_val]
    k_gemm256<0><<<dim3(800), dim3(512), 0, stream>>>(qf_bf, WgvT, b_gen, b_val,
                                                      G_bf, Vt, 512, 10);

    // stage 2: fused attention
    k_attn<<<dim3(2560), dim3(256), 0, stream>>>(qf_bf, G_bf, Vt, wb, bias, O_bf);

    // stage 3: out = O @ W_out + b_out + qf
    k_gemm256<2><<<dim3(160), dim3(512), 0, stream>>>(O_bf, WoT, b_out, qf,
                                                      out, nullptr, 2048, 2);
}